// Round 4
// baseline (72.921 us; speedup 1.0000x reference)
//
#include <hip/hip_runtime.h>
#include <math.h>

#define NN 256
#define NF 24
#define NFEAT 23
#define RCUT 6.0f
#define PI_F 3.14159265358979323846f
#define NSEG 8

// acc[7..22] angular: (eta a/b)x(zeta1-,zeta1+,zeta4-,zeta4+), triple then pair
__device__ __forceinline__ void pair_body(const float4 gj, const float4 wj,
                                          const float4 g, const float4 w,
                                          float* acc)
{
    const float ddx = gj.x - g.x, ddy = gj.y - g.y, ddz = gj.z - g.z;
    const float sqjk = ddx * ddx + ddy * ddy + ddz * ddz;
    const float rjk = sqrtf(sqjk);
    const float fcjk = (rjk < RCUT) ? 0.5f * (__cosf((PI_F / RCUT) * rjk) + 1.0f) : 0.0f;
    const float dot = gj.x * g.x + gj.y * g.y + gj.z * g.z;
    const float cost = dot * gj.w * g.w;
    const float base = wj.x * w.x;        // fcr_ij * fcr_ik
    const float f3 = base * fcjk;
    const float e2a = wj.y * w.y;         // exp(-0.01*(sq_ij+sq_ik))
    const float e2b = wj.z * w.z;         // exp(-0.1 *(sq_ij+sq_ik))
    const float e3a = e2a * __expf(-0.01f * sqjk);
    const float e3b = e2b * __expf(-0.1f * sqjk);
    const float c1m = fmaxf(1.0f - cost, 0.0f);
    const float c1p = fmaxf(1.0f + cost, 0.0f);
    const float c2m = c1m * c1m, c2p = c1p * c1p;
    const float c4m = c2m * c2m, c4p = c2p * c2p;
    const float w3a = e3a * f3, w3b = e3b * f3;
    const float w2a = e2a * base, w2b = e2b * base;
    acc[7]  += c1m * w3a;  acc[8]  += c1p * w3a;
    acc[9]  += c4m * w3a;  acc[10] += c4p * w3a;
    acc[11] += c1m * w3b;  acc[12] += c1p * w3b;
    acc[13] += c4m * w3b;  acc[14] += c4p * w3b;
    acc[15] += c1m * w2a;  acc[16] += c1p * w2a;
    acc[17] += c4m * w2a;  acc[18] += c4p * w2a;
    acc[19] += c1m * w2b;  acc[20] += c1p * w2b;
    acc[21] += c4m * w2b;  acc[22] += c4p * w2b;
}

// one wave (64 threads) per block; grid (NN, B, NSEG) -> 4096 fully-active waves
__global__ __launch_bounds__(64) void feat_kernel(
    const float* __restrict__ coords,  // [B,N,3]
    float* __restrict__ ws)            // [B,N,NSEG,NFEAT] partials
{
    const int i    = blockIdx.x;
    const int b    = blockIdx.y;
    const int seg  = blockIdx.z;
    const int lane = threadIdx.x;      // 0..63

    __shared__ float4 geo[NN];   // compacted: dx, dy, dz, rinv   (dvec = c_i - c_j)
    __shared__ float4 wgt[NN];   // compacted: fc, exp(-.01 r2), exp(-.1 r2), 0
    __shared__ float red[NFEAT];

    const float* cb = coords + (size_t)b * NN * 3;
    const float xi = cb[i * 3 + 0], yi = cb[i * 3 + 1], zi = cb[i * 3 + 2];

    float acc[NFEAT];
#pragma unroll
    for (int t = 0; t < NFEAT; t++) acc[t] = 0.0f;

    // deterministic ballot compaction (identical slot order in all NSEG blocks)
    int m = 0;
#pragma unroll
    for (int rnd = 0; rnd < 4; ++rnd) {
        const int j = lane + (rnd << 6);
        const float xj = cb[j * 3 + 0], yj = cb[j * 3 + 1], zj = cb[j * 3 + 2];
        const float dx = xi - xj, dy = yi - yj, dz = zi - zj;
        const float r2 = dx * dx + dy * dy + dz * dz;
        const float r  = sqrtf(r2);
        const bool incut = (j != i) && (r < RCUT);
        const float fc = incut ? 0.5f * (__cosf((PI_F / RCUT) * r) + 1.0f) : 0.0f;
        if (seg == 0) {   // radial features once
            acc[0] += fc;
            acc[1] += __expf(-0.1f * r2) * fc;
            acc[2] += __expf(-1.0f * r2) * fc;
            const float d = r - 2.0f;
            acc[3] += __expf(-0.1f * d * d) * fc;
            acc[4] += __expf(-1.0f * d * d) * fc;
            acc[5] += __cosf(r) * fc;
            acc[6] += __cosf(2.0f * r) * fc;
        }
        const unsigned long long bal = __ballot(incut);
        if (incut) {
            const int p = m + __popcll(bal & ((1ULL << lane) - 1ULL));
            geo[p] = make_float4(dx, dy, dz, 1.0f / r);
            wgt[p] = make_float4(fc, __expf(-0.01f * r2), __expf(-0.1f * r2), 0.0f);
        }
        m += __popcll(bal);
    }
    __syncthreads();

    // round-robin unordered pairing: slot jj pairs with (jj+t)%m, t=1..(m-1)/2
    // covers each unordered pair once; even m adds a half-round at t=m/2 done
    // by jj < m/2 (assigned to last seg). Result x2 folded into reduce scale.
    if (m >= 2) {
        const int Rfull = (m - 1) >> 1;
        const int tlo = 1 + (Rfull * seg) / NSEG;       // NSEG pow2 -> shifts
        const int thi = (Rfull * (seg + 1)) / NSEG;
        const bool halfseg = (seg == NSEG - 1) && ((m & 1) == 0);
        const int mh = m >> 1;
        for (int rnd = 0; rnd < 4; ++rnd) {
            const int jj = lane + (rnd << 6);
            if (jj >= m) break;
            const float4 gj = geo[jj];
            const float4 wj = wgt[jj];
            for (int t = tlo; t <= thi; ++t) {
                int kk = jj + t; if (kk >= m) kk -= m;
                pair_body(gj, wj, geo[kk], wgt[kk], acc);
            }
            if (halfseg && jj < mh)
                pair_body(gj, wj, geo[jj + mh], wgt[jj + mh], acc);
        }
    }

    // wave reduction, stage via LDS, 23-dword coalesced store of partials
#pragma unroll
    for (int t = 0; t < NFEAT; t++) {
        float v = acc[t];
        for (int off = 32; off > 0; off >>= 1)
            v += __shfl_down(v, off, 64);
        if (lane == 0) red[t] = v;
    }
    __syncthreads();
    if (lane < NFEAT)
        ws[(((size_t)b * NN + i) * NSEG + seg) * NFEAT + lane] = red[lane];
}

__global__ __launch_bounds__(256) void reduce_kernel(
    const float* __restrict__ Z,      // [N]
    const float* __restrict__ ws,     // [B,N,NSEG,NFEAT]
    float* __restrict__ out)          // [B,N,NF]
{
    const int idx = blockIdx.x * 256 + threadIdx.x;   // over B*NN*NF = 12288
    const int f  = idx % NF;
    const int ai = idx / NF;          // b*NN + i
    if (f == 0) { out[idx] = Z[ai & (NN - 1)]; return; }
    float v = 0.0f;
    const float* p = ws + ((size_t)ai * NSEG) * NFEAT + (f - 1);
#pragma unroll
    for (int s = 0; s < NSEG; ++s) v += p[s * NFEAT];
    if (f >= 8) {
        // unordered-pair x2; per group of 4: (z1,-),(z1,+),(z4,-),(z4,+); 2^(1-4)=0.125
        const int a = (f - 8) & 3;
        v *= (a >= 2) ? 0.25f : 2.0f;
    }
    out[idx] = v;
}

extern "C" void kernel_launch(void* const* d_in, const int* in_sizes, int n_in,
                              void* d_out, int out_size, void* d_ws, size_t ws_size,
                              hipStream_t stream) {
    const float* Z = (const float*)d_in[0];       // [256]
    const float* coords = (const float*)d_in[1];  // [2,256,3]
    float* out = (float*)d_out;                   // [2,256,24]
    float* ws = (float*)d_ws;                     // [2,256,NSEG,23] partials
    dim3 grid(NN, 2, NSEG);
    feat_kernel<<<grid, dim3(64), 0, stream>>>(coords, ws);
    const int total = 2 * NN * NF;                // 12288
    reduce_kernel<<<total / 256, 256, 0, stream>>>(Z, ws, out);
}